// Round 1
// baseline (344.966 us; speedup 1.0000x reference)
//
#include <hip/hip_runtime.h>
#include <stdint.h>

// RpnTarget: replicate JAX reference exactly.
//  out[0 .. B*A)           = tags  (float -1/0/+1)
//  out[B*A .. B*A + B*A*6) = deltas (float)
#define NUM_A 1000000
#define NUM_B 4
#define NUM_G 8
#define POS_CAP 1024
#define NEG_CAP 8192          // 64 KiB LDS sort buffer
#define NEG_T0  0.995f        // candidate filter; exact top-800 is provably above this w.h.p.
#define TRAIN_N 800

// ==== JAX Threefry-2x32 reconstruction ====
// JAX_PARTITIONABLE=1 (modern JAX default): split = foldlike (child key = both PRF
//   output words at counts (0,i)); random_bits(32) at index i = w0 ^ w1 of PRF(0,i).
// JAX_PARTITIONABLE=0 (legacy): split/bits use half-split iota counts.
#define JAX_PARTITIONABLE 1
#define PART_BITS_MODE 0      // 0: w0^w1   1: w0   2: w1   (fallback probes)

__host__ __device__ inline void tf2x32(uint32_t k0, uint32_t k1, uint32_t x0,
                                       uint32_t x1, uint32_t* o0, uint32_t* o1) {
  uint32_t ks2 = k0 ^ k1 ^ 0x1BD11BDAu;
#define TF_R(r) x0 += x1; x1 = (x1 << (r)) | (x1 >> (32 - (r))); x1 ^= x0;
  x0 += k0; x1 += k1;
  TF_R(13) TF_R(15) TF_R(26) TF_R(6)
  x0 += k1;  x1 += ks2 + 1u;
  TF_R(17) TF_R(29) TF_R(16) TF_R(24)
  x0 += ks2; x1 += k0 + 2u;
  TF_R(13) TF_R(15) TF_R(26) TF_R(6)
  x0 += k0;  x1 += k1 + 3u;
  TF_R(17) TF_R(29) TF_R(16) TF_R(24)
  x0 += k1;  x1 += ks2 + 4u;
  TF_R(13) TF_R(15) TF_R(26) TF_R(6)
  x0 += ks2; x1 += k0 + 5u;
#undef TF_R
  *o0 = x0; *o1 = x1;
}

__device__ inline uint32_t rng_bits(uint32_t k0, uint32_t k1, uint32_t a) {
#if JAX_PARTITIONABLE
  uint32_t w0, w1; tf2x32(k0, k1, 0u, a, &w0, &w1);
#if PART_BITS_MODE == 0
  return w0 ^ w1;
#elif PART_BITS_MODE == 1
  return w0;
#else
  return w1;
#endif
#else
  uint32_t i = (a < 500000u) ? a : a - 500000u;
  uint32_t w0, w1; tf2x32(k0, k1, i, i + 500000u, &w0, &w1);
  return (a < 500000u) ? w0 : w1;
#endif
}

struct KeySet { uint32_t kp0[NUM_B], kp1[NUM_B], kn0[NUM_B], kn1[NUM_B]; };

static KeySet make_keys() {
  KeySet K;
  uint32_t r0 = 0u, r1 = 42u;   // jax.random.key(42) -> (seed>>32, seed&0xffffffff)
#if JAX_PARTITIONABLE
  for (int b = 0; b < NUM_B; ++b) {
    uint32_t i0, i1;
    tf2x32(r0, r1, 0u, (uint32_t)b, &i0, &i1);        // split(root,4)[b]
    tf2x32(i0, i1, 0u, 0u, &K.kp0[b], &K.kp1[b]);     // split(key)[0] = kp
    tf2x32(i0, i1, 0u, 1u, &K.kn0[b], &K.kn1[b]);     // split(key)[1] = kn
  }
#else
  uint32_t out[8];
  for (int j = 0; j < 4; ++j) {
    uint32_t w0, w1; tf2x32(r0, r1, (uint32_t)j, (uint32_t)(j + 4), &w0, &w1);
    out[j] = w0; out[j + 4] = w1;
  }
  for (int b = 0; b < NUM_B; ++b) {
    uint32_t i0 = out[2 * b], i1 = out[2 * b + 1];
    uint32_t a0, a1, b0, b1;
    tf2x32(i0, i1, 0u, 2u, &a0, &b0);
    tf2x32(i0, i1, 1u, 3u, &a1, &b1);
    K.kp0[b] = a0; K.kp1[b] = a1; K.kn0[b] = b0; K.kn1[b] = b1;
  }
#endif
  return K;
}

// pack: sort key = (u_bits desc, idx asc); argmax g in low 3 bits (doesn't affect order)
__device__ inline uint64_t pack_cand(uint32_t ubits, uint32_t idx, uint32_t arg) {
  return ((uint64_t)ubits << 32) | (uint64_t)(((1048575u - idx) << 3) | arg);
}

__global__ __launch_bounds__(256) void assign_kernel(
    const float* __restrict__ anchors, const float* __restrict__ gt_boxes,
    KeySet K, uint32_t* __restrict__ counters,
    uint64_t* __restrict__ negc, uint64_t* __restrict__ posc) {
  __shared__ float sb[NUM_B * NUM_G * 6];
  __shared__ float svb[NUM_B * NUM_G];
  int t = threadIdx.x;
  if (t < NUM_B * NUM_G * 6) sb[t] = gt_boxes[t];
  __syncthreads();
  if (t < NUM_B * NUM_G) {
    const float* bx = sb + t * 6;
    svb[t] = (bx[3] - bx[0]) * (bx[4] - bx[1]) * (bx[5] - bx[2]);
  }
  __syncthreads();
  uint32_t a = blockIdx.x * blockDim.x + t;
  if (a >= NUM_A) return;
  const float* av = anchors + (size_t)a * 6u;
  float x0 = av[0], x1 = av[1], x2 = av[2], x3 = av[3], x4 = av[4], x5 = av[5];
  float va = (x3 - x0) * (x4 - x1) * (x5 - x2);
  for (int b = 0; b < NUM_B; ++b) {
    float best = -1.0f; int barg = 0;
#pragma unroll
    for (int g = 0; g < NUM_G; ++g) {
      const float* bx = sb + (b * NUM_G + g) * 6;
      float d0 = fmaxf(fminf(bx[3], x3) - fmaxf(bx[0], x0), 0.0f);
      float d1 = fmaxf(fminf(bx[4], x4) - fmaxf(bx[1], x1), 0.0f);
      float d2 = fmaxf(fminf(bx[5], x5) - fmaxf(bx[2], x2), 0.0f);
      float inter = d0 * d1 * d2;
      float iou = inter / ((svb[b * NUM_G + g] + va) - inter);
      if (iou > best) { best = iou; barg = g; }   // strict > keeps first max == argmax
    }
    if (best >= 0.5f) {
      uint32_t bits = rng_bits(K.kp0[b], K.kp1[b], a);
      uint32_t ub = __float_as_uint(__uint_as_float((bits >> 9) | 0x3f800000u) - 1.0f);
      uint32_t slot = atomicAdd(&counters[4 + b], 1u);
      if (slot < POS_CAP) posc[b * POS_CAP + slot] = pack_cand(ub, a, (uint32_t)barg);
    } else if (best <= 0.02f) {
      uint32_t bits = rng_bits(K.kn0[b], K.kn1[b], a);
      float u = __uint_as_float((bits >> 9) | 0x3f800000u) - 1.0f;
      if (u >= NEG_T0) {
        uint32_t slot = atomicAdd(&counters[b], 1u);
        if (slot < NEG_CAP) negc[b * NEG_CAP + slot] = pack_cand(__float_as_uint(u), a, 0u);
      }
    }
  }
}

__device__ inline void bitonic_desc(uint64_t* s, int n) {
  int t = threadIdx.x, nt = blockDim.x;
  for (int k = 2; k <= n; k <<= 1) {
    for (int j = k >> 1; j > 0; j >>= 1) {
      for (int i = t; i < n; i += nt) {
        int ixj = i ^ j;
        if (ixj > i) {
          uint64_t va = s[i], vb = s[ixj];
          bool up = ((i & k) == 0);
          if (up ? (va < vb) : (va > vb)) { s[i] = vb; s[ixj] = va; }
        }
      }
      __syncthreads();
    }
  }
}

__global__ __launch_bounds__(1024) void finalize_kernel(
    const float* __restrict__ anchors, const float* __restrict__ gt_boxes,
    float* __restrict__ tags, float* __restrict__ deltas,
    const uint32_t* __restrict__ counters,
    const uint64_t* __restrict__ negc, const uint64_t* __restrict__ posc) {
  __shared__ uint64_t s[NEG_CAP];   // 64 KiB
  int b = blockIdx.x, t = threadIdx.x;

  // ---- positives: sort all eligible, take top-2 ----
  uint32_t pcnt = counters[4 + b]; if (pcnt > POS_CAP) pcnt = POS_CAP;
  if (t < POS_CAP) s[t] = (t < (int)pcnt) ? posc[b * POS_CAP + t] : 0ull;
  __syncthreads();
  bitonic_desc(s, POS_CAP);
  int pos_num = (int)pcnt < 2 ? (int)pcnt : 2;
  if (t < pos_num) {
    uint32_t low = (uint32_t)s[t];
    uint32_t idx = 1048575u - (low >> 3);
    uint32_t arg = low & 7u;
    tags[(size_t)b * NUM_A + idx] = 1.0f;
    const float* av = anchors + (size_t)idx * 6u;
    const float* gv = gt_boxes + ((size_t)b * NUM_G + arg) * 6u;
    float* dv = deltas + ((size_t)b * NUM_A + idx) * 6u;
#pragma unroll
    for (int k = 0; k < 3; ++k) {
      float ac  = (av[k] + av[k + 3]) * 0.5f;
      float asz = av[k + 3] - av[k];
      float gc  = (gv[k] + gv[k + 3]) * 0.5f;
      float gs  = gv[k + 3] - gv[k];
      dv[k]     = (gc - ac) / asz;
      dv[k + 3] = logf(gs / asz);
    }
  }
  __syncthreads();

  // ---- negatives: sort candidates (superset of exact top-800), tag first 800-pos_num ----
  uint32_t ncnt = counters[b]; if (ncnt > NEG_CAP) ncnt = NEG_CAP;
  for (int i = t; i < NEG_CAP; i += blockDim.x)
    s[i] = (i < (int)ncnt) ? negc[b * NEG_CAP + i] : 0ull;
  __syncthreads();
  bitonic_desc(s, NEG_CAP);
  int ntag = TRAIN_N - pos_num; if (ntag > (int)ncnt) ntag = (int)ncnt;
  if (t < ntag) {
    uint32_t low = (uint32_t)s[t];
    uint32_t idx = 1048575u - (low >> 3);
    tags[(size_t)b * NUM_A + idx] = -1.0f;
  }
}

extern "C" void kernel_launch(void* const* d_in, const int* in_sizes, int n_in,
                              void* d_out, int out_size, void* d_ws, size_t ws_size,
                              hipStream_t stream) {
  const float* anchors  = (const float*)d_in[0];
  const float* gt_boxes = (const float*)d_in[1];
  // d_in[2] = gt_labels: unused by the reference forward.
  float* out = (float*)d_out;
  float* tags = out;
  float* deltas = out + (size_t)NUM_B * NUM_A;

  uint32_t* counters = (uint32_t*)d_ws;                              // 8 x u32
  uint64_t* negc = (uint64_t*)((char*)d_ws + 256);                   // 4 x 8192 x u64
  uint64_t* posc = (uint64_t*)((char*)d_ws + 256 + (size_t)NUM_B * NEG_CAP * 8);

  hipMemsetAsync(d_out, 0, (size_t)out_size * sizeof(float), stream);
  hipMemsetAsync(d_ws, 0, 64, stream);

  KeySet K = make_keys();   // pure host-side Threefry, deterministic

  assign_kernel<<<(NUM_A + 255) / 256, 256, 0, stream>>>(
      anchors, gt_boxes, K, counters, negc, posc);
  finalize_kernel<<<NUM_B, 1024, 0, stream>>>(
      anchors, gt_boxes, tags, deltas, counters, negc, posc);
}

// Round 3
// 285.123 us; speedup vs baseline: 1.2099x; 1.2099x over previous
//
#include <hip/hip_runtime.h>
#include <stdint.h>

// RpnTarget — exact JAX reference replication.
//  out[0 .. B*A)           = tags  (-1/0/+1, written as float)
//  out[B*A .. B*A + B*A*6) = deltas
#define NUM_A 1000000
#define NUM_B 4
#define NUM_G 8
#define POS_CAP 1024
#define NEG_CAP 8192
#define NEG_T0  0.995f     // known-good candidate filter (R1 passed with this)
#define TRAIN_N 800

// ==== JAX Threefry-2x32 (partitionable scheme; verified exact in R1) ====
__host__ __device__ inline void tf2x32(uint32_t k0, uint32_t k1, uint32_t x0,
                                       uint32_t x1, uint32_t* o0, uint32_t* o1) {
  uint32_t ks2 = k0 ^ k1 ^ 0x1BD11BDAu;
#define TF_R(r) x0 += x1; x1 = (x1 << (r)) | (x1 >> (32 - (r))); x1 ^= x0;
  x0 += k0; x1 += k1;
  TF_R(13) TF_R(15) TF_R(26) TF_R(6)
  x0 += k1;  x1 += ks2 + 1u;
  TF_R(17) TF_R(29) TF_R(16) TF_R(24)
  x0 += ks2; x1 += k0 + 2u;
  TF_R(13) TF_R(15) TF_R(26) TF_R(6)
  x0 += k0;  x1 += k1 + 3u;
  TF_R(17) TF_R(29) TF_R(16) TF_R(24)
  x0 += k1;  x1 += ks2 + 4u;
  TF_R(13) TF_R(15) TF_R(26) TF_R(6)
  x0 += ks2; x1 += k0 + 5u;
#undef TF_R
  *o0 = x0; *o1 = x1;
}

__device__ inline uint32_t rng_bits(uint32_t k0, uint32_t k1, uint32_t a) {
  uint32_t w0, w1; tf2x32(k0, k1, 0u, a, &w0, &w1);
  return w0 ^ w1;
}

struct KeySet { uint32_t kp0[NUM_B], kp1[NUM_B], kn0[NUM_B], kn1[NUM_B]; };

static KeySet make_keys() {
  KeySet K;
  uint32_t r0 = 0u, r1 = 42u;   // jax.random.key(42)
  for (int b = 0; b < NUM_B; ++b) {
    uint32_t i0, i1;
    tf2x32(r0, r1, 0u, (uint32_t)b, &i0, &i1);        // split(root,4)[b]
    tf2x32(i0, i1, 0u, 0u, &K.kp0[b], &K.kp1[b]);     // split(key)[0] = kp
    tf2x32(i0, i1, 0u, 1u, &K.kn0[b], &K.kn1[b]);     // split(key)[1] = kn
  }
  return K;
}

// sort key = (u_bits desc, idx asc); gt-argmax in low 3 bits. Distinct per anchor.
__device__ inline uint64_t pack_cand(uint32_t ubits, uint32_t idx, uint32_t arg) {
  return ((uint64_t)ubits << 32) | (uint64_t)(((1048575u - idx) << 3) | arg);
}

__global__ __launch_bounds__(256) void assign_kernel(
    const float* __restrict__ anchors, const float* __restrict__ gt_boxes,
    KeySet K, uint32_t* __restrict__ counters,
    uint64_t* __restrict__ negc, uint64_t* __restrict__ posc,
    float* __restrict__ tags, float* __restrict__ deltas) {
  // boxes packed 8-wide for ds_read_b128: {lo0,lo1,lo2,hi0,hi1,hi2,vb,0}
  __shared__ float sb2[NUM_B][NUM_G][8];
  int t = threadIdx.x;
  if (t < NUM_B * NUM_G) {
    const float* bx = gt_boxes + t * 6;
    float lo0 = bx[0], lo1 = bx[1], lo2 = bx[2];
    float hi0 = bx[3], hi1 = bx[4], hi2 = bx[5];
    float* d = &sb2[t >> 3][t & 7][0];
    d[0] = lo0; d[1] = lo1; d[2] = lo2; d[3] = hi0; d[4] = hi1; d[5] = hi2;
    d[6] = (hi0 - lo0) * (hi1 - lo1) * (hi2 - lo2); d[7] = 0.f;
  }
  __syncthreads();
  uint32_t a = blockIdx.x * blockDim.x + t;
  if (a >= NUM_A) return;

  const float2* ap = (const float2*)(anchors + (size_t)a * 6u);
  float2 av0 = ap[0], av1 = ap[1], av2 = ap[2];
  float x0 = av0.x, x1 = av0.y, x2 = av1.x, x3 = av1.y, x4 = av2.x, x5 = av2.y;
  float va = (x3 - x0) * (x4 - x1) * (x5 - x2);

  // fused output zeroing (replaces 112 MB hipMemsetAsync dispatch)
  float2 z2 = make_float2(0.f, 0.f);
#pragma unroll
  for (int b = 0; b < NUM_B; ++b) {
    tags[(size_t)b * NUM_A + a] = 0.f;
    float2* dz = (float2*)(deltas + ((size_t)b * NUM_A + a) * 6u);
    dz[0] = z2; dz[1] = z2; dz[2] = z2;
  }

#pragma unroll
  for (int b = 0; b < NUM_B; ++b) {
    // argmax over g via cross-multiplication (no division in the loop);
    // denominators are strictly positive so comparison direction is exact.
    float bi = -1.0f, bd = 1.0f; int barg = 0;
#pragma unroll
    for (int g = 0; g < NUM_G; ++g) {
      const float4* bp = (const float4*)&sb2[b][g][0];
      float4 p0 = bp[0], p1 = bp[1];
      float d0 = fmaxf(fminf(p0.w, x3) - fmaxf(p0.x, x0), 0.0f);
      float d1 = fmaxf(fminf(p1.x, x4) - fmaxf(p0.y, x1), 0.0f);
      float d2 = fmaxf(fminf(p1.y, x5) - fmaxf(p0.z, x2), 0.0f);
      float inter = d0 * d1 * d2;
      float den = (p1.z + va) - inter;         // same assoc as reference
      bool c = (inter * bd) > (bi * den);      // iou_g > best  (exact in reals)
      bi = c ? inter : bi;
      bd = c ? den : bd;
      barg = c ? g : barg;
    }
    float q = bi / bd;   // ONE precise divide; thresholds on rounded quotient like ref
    if (q >= 0.5f) {
      uint32_t bits = rng_bits(K.kp0[b], K.kp1[b], a);
      uint32_t ub = __float_as_uint(__uint_as_float((bits >> 9) | 0x3f800000u) - 1.0f);
      uint32_t slot = atomicAdd(&counters[4 + b], 1u);
      if (slot < POS_CAP) posc[b * POS_CAP + slot] = pack_cand(ub, a, (uint32_t)barg);
    } else if (q <= 0.02f) {
      uint32_t bits = rng_bits(K.kn0[b], K.kn1[b], a);
      float u = __uint_as_float((bits >> 9) | 0x3f800000u) - 1.0f;
      if (u >= NEG_T0) {
        uint32_t slot = atomicAdd(&counters[b], 1u);
        if (slot < NEG_CAP) negc[b * NEG_CAP + slot] = pack_cand(__float_as_uint(u), a, 0u);
      }
    }
  }
}

__global__ __launch_bounds__(1024) void finalize_kernel(
    const float* __restrict__ anchors, const float* __restrict__ gt_boxes,
    float* __restrict__ tags, float* __restrict__ deltas,
    const uint32_t* __restrict__ counters,
    const uint64_t* __restrict__ negc, const uint64_t* __restrict__ posc) {
  __shared__ uint64_t red[1024];
  __shared__ uint32_t hist[256];
  __shared__ uint64_t sh_prefix;
  __shared__ uint32_t sh_rem;
  int b = blockIdx.x, t = threadIdx.x;

  // ---- positives: top-2 by two max-reductions (keys distinct, 0 = sentinel) ----
  uint32_t pcnt = counters[4 + b]; if (pcnt > POS_CAP) pcnt = POS_CAP;
  uint64_t k = (t < (int)pcnt) ? posc[b * POS_CAP + t] : 0ull;
  red[t] = k; __syncthreads();
  for (int s = 512; s > 0; s >>= 1) {
    if (t < s) { uint64_t o = red[t + s]; if (o > red[t]) red[t] = o; }
    __syncthreads();
  }
  uint64_t M1 = red[0]; __syncthreads();
  red[t] = (k == M1) ? 0ull : k; __syncthreads();
  for (int s = 512; s > 0; s >>= 1) {
    if (t < s) { uint64_t o = red[t + s]; if (o > red[t]) red[t] = o; }
    __syncthreads();
  }
  uint64_t M2 = red[0]; __syncthreads();
  int pos_num = (int)pcnt < 2 ? (int)pcnt : 2;
  if (t < pos_num) {
    uint64_t w = (t == 0) ? M1 : M2;
    uint32_t low = (uint32_t)w;
    uint32_t idx = 1048575u - (low >> 3);
    uint32_t arg = low & 7u;
    tags[(size_t)b * NUM_A + idx] = 1.0f;
    const float* av = anchors + (size_t)idx * 6u;
    const float* gv = gt_boxes + ((size_t)b * NUM_G + arg) * 6u;
    float* dv = deltas + ((size_t)b * NUM_A + idx) * 6u;
#pragma unroll
    for (int c = 0; c < 3; ++c) {
      float ac  = (av[c] + av[c + 3]) * 0.5f;
      float asz = av[c + 3] - av[c];
      float gc  = (gv[c] + gv[c + 3]) * 0.5f;
      float gs  = gv[c + 3] - gv[c];
      dv[c]     = (gc - ac) / asz;
      dv[c + 3] = logf(gs / asz);
    }
  }

  // ---- negatives: MSB radix-select of rank (800-pos_num), then tag key > pivot ----
  uint32_t ncnt = counters[b]; if (ncnt > NEG_CAP) ncnt = NEG_CAP;
  const uint64_t* keys = negc + (size_t)b * NEG_CAP;
  int rem0 = TRAIN_N - pos_num;
  uint64_t pivot = 0ull;                       // pivot=0 → tag all (ncnt<=rem0 fallback)
  if ((uint32_t)rem0 < ncnt) {                 // uniform branch: barriers safe
    if (t == 0) { sh_prefix = 0ull; sh_rem = (uint32_t)rem0; }
    __syncthreads();
    for (int r = 7; r >= 0; --r) {
      if (t < 256) hist[t] = 0u;
      __syncthreads();
      uint64_t pfx = sh_prefix;
      uint64_t hmask = (r == 7) ? 0ull : (~0ull << (8 * (r + 1)));
      for (uint32_t i = t; i < ncnt; i += 1024u) {
        uint64_t key = keys[i];
        if ((key & hmask) == pfx)
          atomicAdd(&hist[(uint32_t)(key >> (8 * r)) & 255u], 1u);
      }
      __syncthreads();
      if (t == 0) {
        uint32_t rr = sh_rem, acc = 0; int d = 0;
        for (int v = 255; v >= 0; --v) {
          uint32_t h = hist[v];
          if (rr < acc + h) { d = v; break; }
          acc += h;
        }
        sh_prefix = pfx | ((uint64_t)(uint32_t)d << (8 * r));
        sh_rem = rr - acc;                     // invariant: rem < active count
      }
      __syncthreads();
    }
    pivot = sh_prefix;                         // exactly rem0 distinct keys > pivot
  }
  for (uint32_t i = t; i < ncnt; i += 1024u) {
    uint64_t key = keys[i];
    if (key > pivot) {
      uint32_t low = (uint32_t)key;
      uint32_t idx = 1048575u - (low >> 3);
      tags[(size_t)b * NUM_A + idx] = -1.0f;
    }
  }
}

extern "C" void kernel_launch(void* const* d_in, const int* in_sizes, int n_in,
                              void* d_out, int out_size, void* d_ws, size_t ws_size,
                              hipStream_t stream) {
  const float* anchors  = (const float*)d_in[0];
  const float* gt_boxes = (const float*)d_in[1];
  float* out = (float*)d_out;
  float* tags = out;
  float* deltas = out + (size_t)NUM_B * NUM_A;

  uint32_t* counters = (uint32_t*)d_ws;                              // 8 x u32
  uint64_t* negc = (uint64_t*)((char*)d_ws + 256);                   // B x NEG_CAP x u64
  uint64_t* posc = (uint64_t*)((char*)d_ws + 256 + (size_t)NUM_B * NEG_CAP * 8);

  hipMemsetAsync(d_ws, 0, 64, stream);        // counters only; outputs zeroed in-kernel

  KeySet K = make_keys();

  assign_kernel<<<(NUM_A + 255) / 256, 256, 0, stream>>>(
      anchors, gt_boxes, K, counters, negc, posc, tags, deltas);
  finalize_kernel<<<NUM_B, 1024, 0, stream>>>(
      anchors, gt_boxes, tags, deltas, counters, negc, posc);
}

// Round 4
// 226.001 us; speedup vs baseline: 1.5264x; 1.2616x over previous
//
#include <hip/hip_runtime.h>
#include <stdint.h>

// RpnTarget — exact JAX reference replication.
//  out[0 .. B*A)           = tags  (-1/0/+1, written as float)
//  out[B*A .. B*A + B*A*6) = deltas
#define NUM_A 1000000
#define NUM_B 4
#define NUM_G 8
#define POS_CAP 1024
#define NEG_CAP 8192
#define KPT 32              // finalize keys/thread: 256*32 == NEG_CAP
#define NEG_T0  0.995f      // candidate filter; validated R1/R3
#define TRAIN_N 800

// ==== JAX Threefry-2x32 (partitionable scheme; verified exact R1/R3) ====
__host__ __device__ inline void tf2x32(uint32_t k0, uint32_t k1, uint32_t x0,
                                       uint32_t x1, uint32_t* o0, uint32_t* o1) {
  uint32_t ks2 = k0 ^ k1 ^ 0x1BD11BDAu;
#define TF_R(r) x0 += x1; x1 = (x1 << (r)) | (x1 >> (32 - (r))); x1 ^= x0;
  x0 += k0; x1 += k1;
  TF_R(13) TF_R(15) TF_R(26) TF_R(6)
  x0 += k1;  x1 += ks2 + 1u;
  TF_R(17) TF_R(29) TF_R(16) TF_R(24)
  x0 += ks2; x1 += k0 + 2u;
  TF_R(13) TF_R(15) TF_R(26) TF_R(6)
  x0 += k0;  x1 += k1 + 3u;
  TF_R(17) TF_R(29) TF_R(16) TF_R(24)
  x0 += k1;  x1 += ks2 + 4u;
  TF_R(13) TF_R(15) TF_R(26) TF_R(6)
  x0 += ks2; x1 += k0 + 5u;
#undef TF_R
  *o0 = x0; *o1 = x1;
}

__device__ inline uint32_t rng_bits(uint32_t k0, uint32_t k1, uint32_t a) {
  uint32_t w0, w1; tf2x32(k0, k1, 0u, a, &w0, &w1);
  return w0 ^ w1;
}

struct KeySet { uint32_t kp0[NUM_B], kp1[NUM_B], kn0[NUM_B], kn1[NUM_B]; };

static KeySet make_keys() {
  KeySet K;
  uint32_t r0 = 0u, r1 = 42u;   // jax.random.key(42)
  for (int b = 0; b < NUM_B; ++b) {
    uint32_t i0, i1;
    tf2x32(r0, r1, 0u, (uint32_t)b, &i0, &i1);        // split(root,4)[b]
    tf2x32(i0, i1, 0u, 0u, &K.kp0[b], &K.kp1[b]);     // split(key)[0] = kp
    tf2x32(i0, i1, 0u, 1u, &K.kn0[b], &K.kn1[b]);     // split(key)[1] = kn
  }
  return K;
}

// sort key = (u_bits desc, idx asc); gt-argmax in low 3 bits. Distinct per anchor, never 0.
__device__ inline uint64_t pack_cand(uint32_t ubits, uint32_t idx, uint32_t arg) {
  return ((uint64_t)ubits << 32) | (uint64_t)(((1048575u - idx) << 3) | arg);
}

// grid = (ceil(A/256), B). One thread per (anchor, image): max TLP, minimal
// per-thread serial chain (one threefry, 8 IoUs). Boxes loaded wave-uniformly
// (blockIdx.y) -> scalar regs, no LDS, no barriers.
__global__ __launch_bounds__(256) void assign_kernel(
    const float* __restrict__ anchors, const float* __restrict__ gt_boxes,
    KeySet K, uint32_t* __restrict__ counters,
    uint64_t* __restrict__ negc, uint64_t* __restrict__ posc,
    float* __restrict__ tags, float* __restrict__ deltas) {
  const int b = blockIdx.y;
  float bl0[NUM_G], bl1[NUM_G], bl2[NUM_G], bh0[NUM_G], bh1[NUM_G], bh2[NUM_G], bvb[NUM_G];
  const float* gb = gt_boxes + b * (NUM_G * 6);
#pragma unroll
  for (int g = 0; g < NUM_G; ++g) {
    float l0 = gb[g * 6 + 0], l1 = gb[g * 6 + 1], l2 = gb[g * 6 + 2];
    float h0 = gb[g * 6 + 3], h1 = gb[g * 6 + 4], h2 = gb[g * 6 + 5];
    bl0[g] = l0; bl1[g] = l1; bl2[g] = l2;
    bh0[g] = h0; bh1[g] = h1; bh2[g] = h2;
    bvb[g] = (h0 - l0) * (h1 - l1) * (h2 - l2);
  }
  uint32_t a = blockIdx.x * 256u + threadIdx.x;
  if (a >= NUM_A) return;

  const float2* ap = (const float2*)(anchors + (size_t)a * 6u);
  float2 av0 = ap[0], av1 = ap[1], av2 = ap[2];
  float x0 = av0.x, x1 = av0.y, x2 = av1.x, x3 = av1.y, x4 = av2.x, x5 = av2.y;
  float va = (x3 - x0) * (x4 - x1) * (x5 - x2);

  // fused zeroing of this (b, a)'s outputs
  tags[(size_t)b * NUM_A + a] = 0.f;
  float2 z2 = make_float2(0.f, 0.f);
  float2* dz = (float2*)(deltas + ((size_t)b * NUM_A + a) * 6u);
  dz[0] = z2; dz[1] = z2; dz[2] = z2;

  // argmax via cross-multiplication (1 divide total; validated R3)
  float bi = -1.0f, bd = 1.0f; int barg = 0;
#pragma unroll
  for (int g = 0; g < NUM_G; ++g) {
    float d0 = fmaxf(fminf(bh0[g], x3) - fmaxf(bl0[g], x0), 0.0f);
    float d1 = fmaxf(fminf(bh1[g], x4) - fmaxf(bl1[g], x1), 0.0f);
    float d2 = fmaxf(fminf(bh2[g], x5) - fmaxf(bl2[g], x2), 0.0f);
    float inter = d0 * d1 * d2;
    float den = (bvb[g] + va) - inter;       // same assoc as reference
    bool c = (inter * bd) > (bi * den);
    bi = c ? inter : bi;
    bd = c ? den : bd;
    barg = c ? g : barg;
  }
  float q = bi / bd;
  if (q >= 0.5f) {
    uint32_t bits = rng_bits(K.kp0[b], K.kp1[b], a);
    uint32_t ub = __float_as_uint(__uint_as_float((bits >> 9) | 0x3f800000u) - 1.0f);
    uint32_t slot = atomicAdd(&counters[4 + b], 1u);
    if (slot < POS_CAP) posc[b * POS_CAP + slot] = pack_cand(ub, a, (uint32_t)barg);
  } else if (q <= 0.02f) {
    uint32_t bits = rng_bits(K.kn0[b], K.kn1[b], a);
    float u = __uint_as_float((bits >> 9) | 0x3f800000u) - 1.0f;
    if (u >= NEG_T0) {
      uint32_t slot = atomicAdd(&counters[b], 1u);
      if (slot < NEG_CAP) negc[b * NEG_CAP + slot] = pack_cand(__float_as_uint(u), a, 0u);
    }
  }
}

// 256 threads/block, one block per image. Keys register-staged (static unroll),
// radix-select with PARALLEL suffix-scan (no serial t==0 walk).
__global__ __launch_bounds__(256) void finalize_kernel(
    const float* __restrict__ anchors, const float* __restrict__ gt_boxes,
    float* __restrict__ tags, float* __restrict__ deltas,
    const uint32_t* __restrict__ counters,
    const uint64_t* __restrict__ negc, const uint64_t* __restrict__ posc) {
  __shared__ uint64_t red[256];
  __shared__ uint32_t hist[256];
  __shared__ uint32_t pf[256];
  __shared__ uint64_t sh_pfx;
  __shared__ uint32_t sh_rem;
  int b = blockIdx.x, t = threadIdx.x;

  // ---- positives: top-2 via two max-reductions (keys distinct, 0 = sentinel) ----
  uint32_t pcnt = counters[4 + b]; if (pcnt > POS_CAP) pcnt = POS_CAP;
  uint64_t lm = 0ull;
  for (uint32_t i = t; i < pcnt; i += 256u) {
    uint64_t k = posc[b * POS_CAP + i]; if (k > lm) lm = k;
  }
  red[t] = lm; __syncthreads();
  for (int s = 128; s > 0; s >>= 1) {
    if (t < s) { uint64_t o = red[t + s]; if (o > red[t]) red[t] = o; }
    __syncthreads();
  }
  uint64_t M1 = red[0]; __syncthreads();
  lm = 0ull;
  for (uint32_t i = t; i < pcnt; i += 256u) {
    uint64_t k = posc[b * POS_CAP + i]; if (k != M1 && k > lm) lm = k;
  }
  red[t] = lm; __syncthreads();
  for (int s = 128; s > 0; s >>= 1) {
    if (t < s) { uint64_t o = red[t + s]; if (o > red[t]) red[t] = o; }
    __syncthreads();
  }
  uint64_t M2 = red[0]; __syncthreads();
  int pos_num = (int)pcnt < 2 ? (int)pcnt : 2;
  if (t < pos_num) {
    uint64_t w = (t == 0) ? M1 : M2;
    uint32_t low = (uint32_t)w;
    uint32_t idx = 1048575u - (low >> 3);
    uint32_t arg = low & 7u;
    tags[(size_t)b * NUM_A + idx] = 1.0f;
    const float* av = anchors + (size_t)idx * 6u;
    const float* gv = gt_boxes + ((size_t)b * NUM_G + arg) * 6u;
    float* dv = deltas + ((size_t)b * NUM_A + idx) * 6u;
#pragma unroll
    for (int c = 0; c < 3; ++c) {
      float ac  = (av[c] + av[c + 3]) * 0.5f;
      float asz = av[c + 3] - av[c];
      float gc  = (gv[c] + gv[c + 3]) * 0.5f;
      float gs  = gv[c + 3] - gv[c];
      dv[c]     = (gc - ac) / asz;
      dv[c + 3] = logf(gs / asz);
    }
  }

  // ---- negatives: register-stage keys, radix-select rank (800-pos_num) ----
  uint32_t ncnt = counters[b]; if (ncnt > NEG_CAP) ncnt = NEG_CAP;
  const uint64_t* keys = negc + (size_t)b * NEG_CAP;
  uint64_t kr[KPT];
#pragma unroll
  for (int i = 0; i < KPT; ++i) {
    uint32_t ix = (uint32_t)t + 256u * (uint32_t)i;
    kr[i] = (ix < ncnt) ? keys[ix] : 0ull;       // 0 sentinel < any real key
  }
  uint32_t rem0 = (uint32_t)(TRAIN_N - pos_num);
  uint64_t pivot = 0ull;                          // fallback: tag all real keys
  if (rem0 < ncnt) {                              // block-uniform branch
    if (t == 0) { sh_pfx = 0ull; sh_rem = rem0; }
    __syncthreads();
    for (int r = 7; r >= 0; --r) {
      uint64_t pfx = sh_pfx; uint32_t rem = sh_rem;
      hist[t] = 0u; __syncthreads();
      uint64_t hmask = (r == 7) ? 0ull : (~0ull << (8 * (r + 1)));
#pragma unroll
      for (int i = 0; i < KPT; ++i) {
        uint64_t k = kr[i];
        if ((k & hmask) == pfx)
          atomicAdd(&hist[(uint32_t)(k >> (8 * r)) & 255u], 1u);
      }
      __syncthreads();
      uint32_t mycnt = hist[t];
      pf[t] = mycnt; __syncthreads();
      for (int s = 1; s < 256; s <<= 1) {         // inclusive suffix-sum
        uint32_t add = (t + s < 256) ? pf[t + s] : 0u;
        __syncthreads();
        pf[t] += add; __syncthreads();
      }
      uint32_t se = (t < 255) ? pf[t + 1] : 0u;   // count of keys with digit > t
      if (se <= rem && rem < se + mycnt) {        // exactly one thread matches
        sh_pfx = pfx | ((uint64_t)(uint32_t)t << (8 * r));
        sh_rem = rem - se;
      }
      __syncthreads();
    }
    pivot = sh_pfx;                               // key of descending-rank rem0
  }
#pragma unroll
  for (int i = 0; i < KPT; ++i) {
    uint64_t k = kr[i];
    if (k > pivot) {                              // exactly rem0 keys (or all, fallback)
      uint32_t low = (uint32_t)k;
      uint32_t idx = 1048575u - (low >> 3);
      tags[(size_t)b * NUM_A + idx] = -1.0f;
    }
  }
}

extern "C" void kernel_launch(void* const* d_in, const int* in_sizes, int n_in,
                              void* d_out, int out_size, void* d_ws, size_t ws_size,
                              hipStream_t stream) {
  const float* anchors  = (const float*)d_in[0];
  const float* gt_boxes = (const float*)d_in[1];
  float* out = (float*)d_out;
  float* tags = out;
  float* deltas = out + (size_t)NUM_B * NUM_A;

  uint32_t* counters = (uint32_t*)d_ws;                              // 8 x u32
  uint64_t* negc = (uint64_t*)((char*)d_ws + 256);                   // B x NEG_CAP x u64
  uint64_t* posc = (uint64_t*)((char*)d_ws + 256 + (size_t)NUM_B * NEG_CAP * 8);

  hipMemsetAsync(d_ws, 0, 64, stream);        // counters only

  KeySet K = make_keys();

  dim3 grid((NUM_A + 255) / 256, NUM_B);
  assign_kernel<<<grid, 256, 0, stream>>>(
      anchors, gt_boxes, K, counters, negc, posc, tags, deltas);
  finalize_kernel<<<NUM_B, 256, 0, stream>>>(
      anchors, gt_boxes, tags, deltas, counters, negc, posc);
}

// Round 5
// 113.366 us; speedup vs baseline: 3.0429x; 1.9935x over previous
//
#include <hip/hip_runtime.h>
#include <stdint.h>

// RpnTarget — exact JAX reference replication.
//  out[0 .. B*A)           = tags  (-1/0/+1, written as float)
//  out[B*A .. B*A + B*A*6) = deltas
#define NUM_A 1000000
#define NUM_B 4
#define NUM_G 8
#define NSEG 64              // segments per image; each counter on its own 128B line
#define NEG_SEG_CAP 160      // mean ~74/seg, sigma ~8.6 -> +10 sigma margin
#define POS_SEG_CAP 64
#define NEG_CAP 8192         // finalize total cap (same as validated R4)
#define POS_SM_CAP 1024      // same guarantee as R1-R4 POS_CAP
#define KPT 32               // 256*32 == NEG_CAP
#define NEG_T0  0.995f       // candidate filter; validated R1/R3/R4
#define TRAIN_N 800

// ==== JAX Threefry-2x32 (partitionable scheme; verified exact R1/R3/R4) ====
__host__ __device__ inline void tf2x32(uint32_t k0, uint32_t k1, uint32_t x0,
                                       uint32_t x1, uint32_t* o0, uint32_t* o1) {
  uint32_t ks2 = k0 ^ k1 ^ 0x1BD11BDAu;
#define TF_R(r) x0 += x1; x1 = (x1 << (r)) | (x1 >> (32 - (r))); x1 ^= x0;
  x0 += k0; x1 += k1;
  TF_R(13) TF_R(15) TF_R(26) TF_R(6)
  x0 += k1;  x1 += ks2 + 1u;
  TF_R(17) TF_R(29) TF_R(16) TF_R(24)
  x0 += ks2; x1 += k0 + 2u;
  TF_R(13) TF_R(15) TF_R(26) TF_R(6)
  x0 += k0;  x1 += k1 + 3u;
  TF_R(17) TF_R(29) TF_R(16) TF_R(24)
  x0 += k1;  x1 += ks2 + 4u;
  TF_R(13) TF_R(15) TF_R(26) TF_R(6)
  x0 += ks2; x1 += k0 + 5u;
#undef TF_R
  *o0 = x0; *o1 = x1;
}

__device__ inline uint32_t rng_bits(uint32_t k0, uint32_t k1, uint32_t a) {
  uint32_t w0, w1; tf2x32(k0, k1, 0u, a, &w0, &w1);
  return w0 ^ w1;
}

struct KeySet { uint32_t kp0[NUM_B], kp1[NUM_B], kn0[NUM_B], kn1[NUM_B]; };

static KeySet make_keys() {
  KeySet K;
  uint32_t r0 = 0u, r1 = 42u;   // jax.random.key(42)
  for (int b = 0; b < NUM_B; ++b) {
    uint32_t i0, i1;
    tf2x32(r0, r1, 0u, (uint32_t)b, &i0, &i1);        // split(root,4)[b]
    tf2x32(i0, i1, 0u, 0u, &K.kp0[b], &K.kp1[b]);     // split(key)[0] = kp
    tf2x32(i0, i1, 0u, 1u, &K.kn0[b], &K.kn1[b]);     // split(key)[1] = kn
  }
  return K;
}

// sort key = (u_bits desc, idx asc); gt-argmax in low 3 bits. Distinct per anchor, never 0.
__device__ inline uint64_t pack_cand(uint32_t ubits, uint32_t idx, uint32_t arg) {
  return ((uint64_t)ubits << 32) | (uint64_t)(((1048575u - idx) << 3) | arg);
}

// ws layout (bytes):
//   0       : neg counters  [B][NSEG] at 128B stride  (32 KiB)
//   32768   : pos counters  [B][NSEG] at 128B stride  (32 KiB)
//   65536   : negc [B][NSEG][NEG_SEG_CAP] u64         (320 KiB)
//   393216  : posc [B][NSEG][POS_SEG_CAP] u64         (128 KiB)
#define WS_POSCNT 32768
#define WS_NEGC   65536
#define WS_POSC   393216

__global__ __launch_bounds__(256) void assign_kernel(
    const float* __restrict__ anchors, const float* __restrict__ gt_boxes,
    KeySet K, uint32_t* __restrict__ cnt_base,
    uint64_t* __restrict__ negc, uint64_t* __restrict__ posc,
    float* __restrict__ tags, float* __restrict__ deltas) {
  const int seg = blockIdx.x & (NSEG - 1);     // candidate segment (atomic spreading)
  uint32_t a = blockIdx.x * 256u + threadIdx.x;
  if (a >= NUM_A) return;

  const float2* ap = (const float2*)(anchors + (size_t)a * 6u);
  float2 av0 = ap[0], av1 = ap[1], av2 = ap[2];
  float x0 = av0.x, x1 = av0.y, x2 = av1.x, x3 = av1.y, x4 = av2.x, x5 = av2.y;
  float va = (x3 - x0) * (x4 - x1) * (x5 - x2);

  // fused output zeroing (110 MB streaming writes)
  float2 z2 = make_float2(0.f, 0.f);
#pragma unroll
  for (int b = 0; b < NUM_B; ++b) {
    tags[(size_t)b * NUM_A + a] = 0.f;
    float2* dz = (float2*)(deltas + ((size_t)b * NUM_A + a) * 6u);
    dz[0] = z2; dz[1] = z2; dz[2] = z2;
  }

#pragma unroll
  for (int b = 0; b < NUM_B; ++b) {
    const float* gb = gt_boxes + b * (NUM_G * 6);   // uniform -> scalar loads
    float bi = -1.0f, bd = 1.0f; int barg = 0;
#pragma unroll
    for (int g = 0; g < NUM_G; ++g) {
      float l0 = gb[g * 6 + 0], l1 = gb[g * 6 + 1], l2 = gb[g * 6 + 2];
      float h0 = gb[g * 6 + 3], h1 = gb[g * 6 + 4], h2 = gb[g * 6 + 5];
      float d0 = fmaxf(fminf(h0, x3) - fmaxf(l0, x0), 0.0f);
      float d1 = fmaxf(fminf(h1, x4) - fmaxf(l1, x1), 0.0f);
      float d2 = fmaxf(fminf(h2, x5) - fmaxf(l2, x2), 0.0f);
      float inter = d0 * d1 * d2;
      float vb = (h0 - l0) * (h1 - l1) * (h2 - l2);
      float den = (vb + va) - inter;           // same assoc as reference
      bool c = (inter * bd) > (bi * den);      // cross-mult argmax (validated)
      bi = c ? inter : bi;
      bd = c ? den : bd;
      barg = c ? g : barg;
    }
    float q = bi / bd;                         // one precise divide
    if (q >= 0.5f) {
      uint32_t bits = rng_bits(K.kp0[b], K.kp1[b], a);
      uint32_t ub = __float_as_uint(__uint_as_float((bits >> 9) | 0x3f800000u) - 1.0f);
      uint32_t* c32 = cnt_base + (WS_POSCNT / 4) + (b * NSEG + seg) * 32;
      uint32_t slot = atomicAdd(c32, 1u);
      if (slot < POS_SEG_CAP)
        posc[((size_t)b * NSEG + seg) * POS_SEG_CAP + slot] = pack_cand(ub, a, (uint32_t)barg);
    } else if (q <= 0.02f) {
      uint32_t bits = rng_bits(K.kn0[b], K.kn1[b], a);
      float u = __uint_as_float((bits >> 9) | 0x3f800000u) - 1.0f;
      if (u >= NEG_T0) {
        uint32_t* c32 = cnt_base + (b * NSEG + seg) * 32;
        uint32_t slot = atomicAdd(c32, 1u);
        if (slot < NEG_SEG_CAP)
          negc[((size_t)b * NSEG + seg) * NEG_SEG_CAP + slot] = pack_cand(__float_as_uint(u), a, 0u);
      }
    }
  }
}

// one 256-thread block per image: compact segments -> LDS, then validated selects.
__global__ __launch_bounds__(256) void finalize_kernel(
    const float* __restrict__ anchors, const float* __restrict__ gt_boxes,
    float* __restrict__ tags, float* __restrict__ deltas,
    const uint32_t* __restrict__ cnt_base,
    const uint64_t* __restrict__ negc, const uint64_t* __restrict__ posc) {
  __shared__ uint64_t sm[NEG_CAP];        // 64 KiB
  __shared__ uint64_t psm[POS_SM_CAP];    // 8 KiB
  __shared__ uint64_t red[256];
  __shared__ uint32_t hist[256];
  __shared__ uint32_t pf[256];
  __shared__ uint64_t sh_pfx;
  __shared__ uint32_t sh_rem;
  int b = blockIdx.x, t = threadIdx.x;

  // ---- compact positives: segments -> psm ----
  uint32_t ptot = 0;
  {
    uint32_t off = 0;
#pragma unroll
    for (int s = 0; s < NSEG; ++s) {     // all threads compute same offsets (cheap)
      uint32_t c = cnt_base[(WS_POSCNT / 4) + (b * NSEG + s) * 32];
      if (c > POS_SEG_CAP) c = POS_SEG_CAP;
      uint32_t lim = (off + c > POS_SM_CAP) ? (POS_SM_CAP - off) : c;
      for (uint32_t i = t; i < lim; i += 256u)
        psm[off + i] = posc[((size_t)b * NSEG + s) * POS_SEG_CAP + i];
      off += lim;
    }
    ptot = off;
  }
  // ---- compact negatives: segments -> sm ----
  uint32_t ncnt = 0;
  {
    uint32_t off = 0;
#pragma unroll
    for (int s = 0; s < NSEG; ++s) {
      uint32_t c = cnt_base[(b * NSEG + s) * 32];
      if (c > NEG_SEG_CAP) c = NEG_SEG_CAP;
      uint32_t lim = (off + c > NEG_CAP) ? (NEG_CAP - off) : c;
      for (uint32_t i = t; i < lim; i += 256u)
        sm[off + i] = negc[((size_t)b * NSEG + s) * NEG_SEG_CAP + i];
      off += lim;
    }
    ncnt = off;
  }
  __syncthreads();

  // ---- positives: top-2 via two max-reductions (keys distinct, 0 = sentinel) ----
  uint64_t lm = 0ull;
  for (uint32_t i = t; i < ptot; i += 256u) { uint64_t k = psm[i]; if (k > lm) lm = k; }
  red[t] = lm; __syncthreads();
  for (int s = 128; s > 0; s >>= 1) {
    if (t < s) { uint64_t o = red[t + s]; if (o > red[t]) red[t] = o; }
    __syncthreads();
  }
  uint64_t M1 = red[0]; __syncthreads();
  lm = 0ull;
  for (uint32_t i = t; i < ptot; i += 256u) {
    uint64_t k = psm[i]; if (k != M1 && k > lm) lm = k;
  }
  red[t] = lm; __syncthreads();
  for (int s = 128; s > 0; s >>= 1) {
    if (t < s) { uint64_t o = red[t + s]; if (o > red[t]) red[t] = o; }
    __syncthreads();
  }
  uint64_t M2 = red[0]; __syncthreads();
  int pos_num = (int)ptot < 2 ? (int)ptot : 2;
  if (t < pos_num) {
    uint64_t w = (t == 0) ? M1 : M2;
    uint32_t low = (uint32_t)w;
    uint32_t idx = 1048575u - (low >> 3);
    uint32_t arg = low & 7u;
    tags[(size_t)b * NUM_A + idx] = 1.0f;
    const float* av = anchors + (size_t)idx * 6u;
    const float* gv = gt_boxes + ((size_t)b * NUM_G + arg) * 6u;
    float* dv = deltas + ((size_t)b * NUM_A + idx) * 6u;
#pragma unroll
    for (int c = 0; c < 3; ++c) {
      float ac  = (av[c] + av[c + 3]) * 0.5f;
      float asz = av[c + 3] - av[c];
      float gc  = (gv[c] + gv[c + 3]) * 0.5f;
      float gs  = gv[c + 3] - gv[c];
      dv[c]     = (gc - ac) / asz;
      dv[c + 3] = logf(gs / asz);
    }
  }

  // ---- negatives: register-stage keys, radix-select rank (800-pos_num) (validated R4) ----
  uint64_t kr[KPT];
#pragma unroll
  for (int i = 0; i < KPT; ++i) {
    uint32_t ix = (uint32_t)t + 256u * (uint32_t)i;
    kr[i] = (ix < ncnt) ? sm[ix] : 0ull;          // 0 sentinel < any real key
  }
  uint32_t rem0 = (uint32_t)(TRAIN_N - pos_num);
  uint64_t pivot = 0ull;                          // fallback: tag all real keys
  if (rem0 < ncnt) {                              // block-uniform branch
    if (t == 0) { sh_pfx = 0ull; sh_rem = rem0; }
    __syncthreads();
    for (int r = 7; r >= 0; --r) {
      uint64_t pfx = sh_pfx; uint32_t rem = sh_rem;
      hist[t] = 0u; __syncthreads();
      uint64_t hmask = (r == 7) ? 0ull : (~0ull << (8 * (r + 1)));
#pragma unroll
      for (int i = 0; i < KPT; ++i) {
        uint64_t k = kr[i];
        if ((k & hmask) == pfx)
          atomicAdd(&hist[(uint32_t)(k >> (8 * r)) & 255u], 1u);
      }
      __syncthreads();
      uint32_t mycnt = hist[t];
      pf[t] = mycnt; __syncthreads();
      for (int s = 1; s < 256; s <<= 1) {         // inclusive suffix-sum
        uint32_t add = (t + s < 256) ? pf[t + s] : 0u;
        __syncthreads();
        pf[t] += add; __syncthreads();
      }
      uint32_t se = (t < 255) ? pf[t + 1] : 0u;   // keys with digit > t
      if (se <= rem && rem < se + mycnt) {        // exactly one thread matches
        sh_pfx = pfx | ((uint64_t)(uint32_t)t << (8 * r));
        sh_rem = rem - se;
      }
      __syncthreads();
    }
    pivot = sh_pfx;
  }
#pragma unroll
  for (int i = 0; i < KPT; ++i) {
    uint64_t k = kr[i];
    if (k > pivot) {                              // exactly rem0 keys (or all, fallback)
      uint32_t low = (uint32_t)k;
      uint32_t idx = 1048575u - (low >> 3);
      tags[(size_t)b * NUM_A + idx] = -1.0f;
    }
  }
}

extern "C" void kernel_launch(void* const* d_in, const int* in_sizes, int n_in,
                              void* d_out, int out_size, void* d_ws, size_t ws_size,
                              hipStream_t stream) {
  const float* anchors  = (const float*)d_in[0];
  const float* gt_boxes = (const float*)d_in[1];
  float* out = (float*)d_out;
  float* tags = out;
  float* deltas = out + (size_t)NUM_B * NUM_A;

  uint32_t* cnt_base = (uint32_t*)d_ws;
  uint64_t* negc = (uint64_t*)((char*)d_ws + WS_NEGC);
  uint64_t* posc = (uint64_t*)((char*)d_ws + WS_POSC);

  hipMemsetAsync(d_ws, 0, 2 * WS_POSCNT, stream);   // both counter regions (64 KiB)

  KeySet K = make_keys();

  assign_kernel<<<(NUM_A + 255) / 256, 256, 0, stream>>>(
      anchors, gt_boxes, K, cnt_base, negc, posc, tags, deltas);
  finalize_kernel<<<NUM_B, 256, 0, stream>>>(
      anchors, gt_boxes, tags, deltas, cnt_base, negc, posc);
}

// Round 7
// 75.665 us; speedup vs baseline: 4.5591x; 1.4983x over previous
//
#include <hip/hip_runtime.h>
#include <stdint.h>

// RpnTarget — exact JAX reference replication.
//  out[0 .. B*A)           = tags  (-1/0/+1, written as float)
//  out[B*A .. B*A + B*A*6) = deltas
#define NUM_A 1000000
#define NUM_B 4
#define NUM_G 8
#define NSEG 64              // segments per image; each counter on its own 128B line
#define NEG_SEG_CAP 128      // mean ~74/seg, sigma ~8.6 -> +6.3 sigma; pow2 for idx math
#define POS_SEG_CAP 64
#define KPTN 32              // 64*128/256 neg slots per thread
#define KPTP 16              // 64*64/256  pos slots per thread
#define NEG_T0  0.995f       // candidate filter; validated R1/R3/R4/R5
#define TRAIN_N 800

// ==== JAX Threefry-2x32 (partitionable scheme; verified exact R1-R5) ====
__host__ __device__ inline void tf2x32(uint32_t k0, uint32_t k1, uint32_t x0,
                                       uint32_t x1, uint32_t* o0, uint32_t* o1) {
  uint32_t ks2 = k0 ^ k1 ^ 0x1BD11BDAu;
#define TF_R(r) x0 += x1; x1 = (x1 << (r)) | (x1 >> (32 - (r))); x1 ^= x0;
  x0 += k0; x1 += k1;
  TF_R(13) TF_R(15) TF_R(26) TF_R(6)
  x0 += k1;  x1 += ks2 + 1u;
  TF_R(17) TF_R(29) TF_R(16) TF_R(24)
  x0 += ks2; x1 += k0 + 2u;
  TF_R(13) TF_R(15) TF_R(26) TF_R(6)
  x0 += k0;  x1 += k1 + 3u;
  TF_R(17) TF_R(29) TF_R(16) TF_R(24)
  x0 += k1;  x1 += ks2 + 4u;
  TF_R(13) TF_R(15) TF_R(26) TF_R(6)
  x0 += ks2; x1 += k0 + 5u;
#undef TF_R
  *o0 = x0; *o1 = x1;
}

__device__ inline uint32_t rng_bits(uint32_t k0, uint32_t k1, uint32_t a) {
  uint32_t w0, w1; tf2x32(k0, k1, 0u, a, &w0, &w1);
  return w0 ^ w1;
}

struct KeySet { uint32_t kp0[NUM_B], kp1[NUM_B], kn0[NUM_B], kn1[NUM_B]; };

static KeySet make_keys() {
  KeySet K;
  uint32_t r0 = 0u, r1 = 42u;   // jax.random.key(42)
  for (int b = 0; b < NUM_B; ++b) {
    uint32_t i0, i1;
    tf2x32(r0, r1, 0u, (uint32_t)b, &i0, &i1);        // split(root,4)[b]
    tf2x32(i0, i1, 0u, 0u, &K.kp0[b], &K.kp1[b]);     // split(key)[0] = kp
    tf2x32(i0, i1, 0u, 1u, &K.kn0[b], &K.kn1[b]);     // split(key)[1] = kn
  }
  return K;
}

// sort key = (u_bits desc, idx asc); gt-argmax in low 3 bits. Distinct per anchor, never 0.
__device__ inline uint64_t pack_cand(uint32_t ubits, uint32_t idx, uint32_t arg) {
  return ((uint64_t)ubits << 32) | (uint64_t)(((1048575u - idx) << 3) | arg);
}

// ws layout (bytes):
//   0       : neg counters  [B][NSEG] at 128B stride  (32 KiB)
//   32768   : pos counters  [B][NSEG] at 128B stride  (32 KiB)
//   65536   : negc [B][NSEG][NEG_SEG_CAP] u64         (256 KiB)
//   327680  : posc [B][NSEG][POS_SEG_CAP] u64         (128 KiB)
#define WS_POSCNT 32768
#define WS_NEGC   65536
#define WS_POSC   327680

__global__ __launch_bounds__(256) void assign_kernel(
    const float* __restrict__ anchors, const float* __restrict__ gt_boxes,
    KeySet K, uint32_t* __restrict__ cnt_base,
    uint64_t* __restrict__ negc, uint64_t* __restrict__ posc,
    float* __restrict__ tags, float* __restrict__ deltas) {
  const int seg = blockIdx.x & (NSEG - 1);     // candidate segment (atomic spreading, R5 win)
  uint32_t a = blockIdx.x * 256u + threadIdx.x;
  if (a >= NUM_A) return;

  const float2* ap = (const float2*)(anchors + (size_t)a * 6u);
  float2 av0 = ap[0], av1 = ap[1], av2 = ap[2];
  float x0 = av0.x, x1 = av0.y, x2 = av1.x, x3 = av1.y, x4 = av2.x, x5 = av2.y;
  float va = (x3 - x0) * (x4 - x1) * (x5 - x2);

  // fused output zeroing (110 MB streaming writes)
  float2 z2 = make_float2(0.f, 0.f);
#pragma unroll
  for (int b = 0; b < NUM_B; ++b) {
    tags[(size_t)b * NUM_A + a] = 0.f;
    float2* dz = (float2*)(deltas + ((size_t)b * NUM_A + a) * 6u);
    dz[0] = z2; dz[1] = z2; dz[2] = z2;
  }

#pragma unroll
  for (int b = 0; b < NUM_B; ++b) {
    const float* gb = gt_boxes + b * (NUM_G * 6);   // uniform -> scalar loads
    float bi = -1.0f, bd = 1.0f; int barg = 0;
#pragma unroll
    for (int g = 0; g < NUM_G; ++g) {
      float l0 = gb[g * 6 + 0], l1 = gb[g * 6 + 1], l2 = gb[g * 6 + 2];
      float h0 = gb[g * 6 + 3], h1 = gb[g * 6 + 4], h2 = gb[g * 6 + 5];
      float d0 = fmaxf(fminf(h0, x3) - fmaxf(l0, x0), 0.0f);
      float d1 = fmaxf(fminf(h1, x4) - fmaxf(l1, x1), 0.0f);
      float d2 = fmaxf(fminf(h2, x5) - fmaxf(l2, x2), 0.0f);
      float inter = d0 * d1 * d2;
      float vb = (h0 - l0) * (h1 - l1) * (h2 - l2);
      float den = (vb + va) - inter;           // same assoc as reference
      bool c = (inter * bd) > (bi * den);      // cross-mult argmax (validated)
      bi = c ? inter : bi;
      bd = c ? den : bd;
      barg = c ? g : barg;
    }
    float q = bi / bd;                         // one precise divide
    if (q >= 0.5f) {
      uint32_t bits = rng_bits(K.kp0[b], K.kp1[b], a);
      uint32_t ub = __float_as_uint(__uint_as_float((bits >> 9) | 0x3f800000u) - 1.0f);
      uint32_t* c32 = cnt_base + (WS_POSCNT / 4) + (b * NSEG + seg) * 32;
      uint32_t slot = atomicAdd(c32, 1u);
      if (slot < POS_SEG_CAP)
        posc[((size_t)b * NSEG + seg) * POS_SEG_CAP + slot] = pack_cand(ub, a, (uint32_t)barg);
    } else if (q <= 0.02f) {
      uint32_t bits = rng_bits(K.kn0[b], K.kn1[b], a);
      float u = __uint_as_float((bits >> 9) | 0x3f800000u) - 1.0f;
      if (u >= NEG_T0) {
        uint32_t* c32 = cnt_base + (b * NSEG + seg) * 32;
        uint32_t slot = atomicAdd(c32, 1u);
        if (slot < NEG_SEG_CAP)
          negc[((size_t)b * NSEG + seg) * NEG_SEG_CAP + slot] = pack_cand(__float_as_uint(u), a, 0u);
      }
    }
  }
}

// One 256-thread block per image. No compaction, no LDS key staging, no histograms:
// keys go straight to registers from the padded segment layout (selection is by VALUE,
// so slot order is irrelevant); pivot found by greedy bitwise rank search over the
// 37 varying key bits using shfl-reduced counts (zero LDS atomics).
__global__ __launch_bounds__(256) void finalize_kernel(
    const float* __restrict__ anchors, const float* __restrict__ gt_boxes,
    float* __restrict__ tags, float* __restrict__ deltas,
    const uint32_t* __restrict__ cnt_base,
    const uint64_t* __restrict__ negc, const uint64_t* __restrict__ posc) {
  __shared__ uint32_t scnt_n[NSEG];
  __shared__ uint32_t scnt_p[NSEG];
  __shared__ uint32_t tot_s[2];
  __shared__ uint32_t wred[4];
  __shared__ uint64_t red[256];
  const int b = blockIdx.x, t = threadIdx.x;
  const int wid = t >> 6, lane = t & 63;

  // ---- parallel counter read + totals (one global latency round) ----
  uint32_t cn = 0, cp = 0;
  if (t < NSEG) {
    cn = cnt_base[(b * NSEG + t) * 32];
    if (cn > NEG_SEG_CAP) cn = NEG_SEG_CAP;
    scnt_n[t] = cn;
  } else if (t < 2 * NSEG) {
    int s = t - NSEG;
    cp = cnt_base[(WS_POSCNT / 4) + (b * NSEG + s) * 32];
    if (cp > POS_SEG_CAP) cp = POS_SEG_CAP;
    scnt_p[s] = cp;
  }
  uint32_t v = (wid == 0) ? cn : cp;           // wave0 sums neg, wave1 sums pos
  for (int s = 1; s < 64; s <<= 1) v += __shfl_xor(v, s, 64);
  if (lane == 0 && wid < 2) tot_s[wid] = v;
  __syncthreads();
  const uint32_t ncnt = tot_s[0];
  const uint32_t ptot = tot_s[1];

  // ---- register-load keys directly from padded segment layout ----
  uint64_t kr[KPTN];
#pragma unroll
  for (int j = 0; j < KPTN; ++j) {
    uint32_t slot = (uint32_t)t + 256u * (uint32_t)j;   // covers 64*128 slots
    uint32_t seg = slot >> 7, i = slot & 127u;
    uint64_t k = 0ull;
    if (i < scnt_n[seg]) k = negc[((size_t)b * NSEG + seg) * NEG_SEG_CAP + i];
    kr[j] = k;
  }
  uint64_t pk[KPTP];
#pragma unroll
  for (int j = 0; j < KPTP; ++j) {
    uint32_t slot = (uint32_t)t + 256u * (uint32_t)j;   // covers 64*64 slots
    uint32_t seg = slot >> 6, i = slot & 63u;
    uint64_t k = 0ull;
    if (i < scnt_p[seg]) k = posc[((size_t)b * NSEG + seg) * POS_SEG_CAP + i];
    pk[j] = k;
  }

  // ---- positives: top-2 via two tree max-reductions (keys distinct, 0 sentinel) ----
  uint64_t m = 0ull;
#pragma unroll
  for (int j = 0; j < KPTP; ++j) if (pk[j] > m) m = pk[j];
  red[t] = m; __syncthreads();
  for (int s = 128; s > 0; s >>= 1) {
    if (t < s) { uint64_t o = red[t + s]; if (o > red[t]) red[t] = o; }
    __syncthreads();
  }
  const uint64_t M1 = red[0]; __syncthreads();
  m = 0ull;
#pragma unroll
  for (int j = 0; j < KPTP; ++j) if (pk[j] != M1 && pk[j] > m) m = pk[j];
  red[t] = m; __syncthreads();
  for (int s = 128; s > 0; s >>= 1) {
    if (t < s) { uint64_t o = red[t + s]; if (o > red[t]) red[t] = o; }
    __syncthreads();
  }
  const uint64_t M2 = red[0]; __syncthreads();

  const uint32_t pos_num = (ptot < 2u) ? ptot : 2u;
  if (t < (int)pos_num) {
    uint64_t w = (t == 0) ? M1 : M2;
    uint32_t low = (uint32_t)w;
    uint32_t idx = 1048575u - (low >> 3);
    uint32_t arg = low & 7u;
    tags[(size_t)b * NUM_A + idx] = 1.0f;
    const float* av = anchors + (size_t)idx * 6u;
    const float* gv = gt_boxes + ((size_t)b * NUM_G + arg) * 6u;
    float* dv = deltas + ((size_t)b * NUM_A + idx) * 6u;
#pragma unroll
    for (int c = 0; c < 3; ++c) {
      float ac  = (av[c] + av[c + 3]) * 0.5f;
      float asz = av[c + 3] - av[c];
      float gc  = (gv[c] + gv[c + 3]) * 0.5f;
      float gs  = gv[c + 3] - gv[c];
      dv[c]     = (gc - ac) / asz;
      dv[c + 3] = logf(gs / asz);
    }
  }

  // ---- negatives: greedy bitwise rank search for pivot (no LDS atomics) ----
  // All real keys share bits 63..49 == 0x1FBF (u in [0.995,1)); bits 31..23 and
  // 2..0 are structurally zero. Pivot = max X with count(keys >= X) >= rem0+1.
  const uint32_t rem0 = TRAIN_N - pos_num;
  uint64_t pivot = 0ull;                        // fallback: tag all real keys
  if (rem0 < ncnt) {                            // block-uniform branch
    uint64_t cur = 0x1FBFull << 49;
    auto step = [&](int bit) {
      uint64_t t64 = cur | (1ull << bit);
      uint32_t c = 0;
#pragma unroll
      for (int j = 0; j < KPTN; ++j) c += (kr[j] >= t64) ? 1u : 0u;
      for (int s = 1; s < 64; s <<= 1) c += __shfl_xor(c, s, 64);
      if (lane == 0) wred[wid] = c;
      __syncthreads();
      c = wred[0] + wred[1] + wred[2] + wred[3];
      __syncthreads();
      if (c >= rem0 + 1u) cur = t64;            // uniform decision
    };
    for (int bit = 48; bit >= 32; --bit) step(bit);  // u_bits low 17 bits
    for (int bit = 22; bit >= 3; --bit) step(bit);   // idx field bits
    pivot = cur;
  }
#pragma unroll
  for (int j = 0; j < KPTN; ++j) {
    uint64_t k = kr[j];
    if (k > pivot) {                            // exactly rem0 keys (or all, fallback)
      uint32_t low = (uint32_t)k;
      uint32_t idx = 1048575u - (low >> 3);
      tags[(size_t)b * NUM_A + idx] = -1.0f;
    }
  }
}

extern "C" void kernel_launch(void* const* d_in, const int* in_sizes, int n_in,
                              void* d_out, int out_size, void* d_ws, size_t ws_size,
                              hipStream_t stream) {
  const float* anchors  = (const float*)d_in[0];
  const float* gt_boxes = (const float*)d_in[1];
  float* out = (float*)d_out;
  float* tags = out;
  float* deltas = out + (size_t)NUM_B * NUM_A;

  uint32_t* cnt_base = (uint32_t*)d_ws;
  uint64_t* negc = (uint64_t*)((char*)d_ws + WS_NEGC);
  uint64_t* posc = (uint64_t*)((char*)d_ws + WS_POSC);

  hipMemsetAsync(d_ws, 0, 2 * WS_POSCNT, stream);   // both counter regions (64 KiB)

  KeySet K = make_keys();

  assign_kernel<<<(NUM_A + 255) / 256, 256, 0, stream>>>(
      anchors, gt_boxes, K, cnt_base, negc, posc, tags, deltas);
  finalize_kernel<<<NUM_B, 256, 0, stream>>>(
      anchors, gt_boxes, tags, deltas, cnt_base, negc, posc);
}